// Round 5
// baseline (50.876 us; speedup 1.0000x reference)
//
#include <hip/hip_runtime.h>

#define N      2304        // T*H*W = 4*24*24
#define CIN    64
#define CHALF  32
#define KT     17          // polynomial powers 0..16
#define TILE   32
#define NBLK   (N / TILE)  // 72 blocks -> all co-resident on 256 CUs

// ---------------------------------------------------------------------------
// Device-scope grid barrier. Counters are zeroed by hipMemsetAsync before each
// launch, so a plain arrive-and-spin is deterministic across graph replays.
// ---------------------------------------------------------------------------
__device__ __forceinline__ void grid_barrier(unsigned* ctr, unsigned nblk) {
    __syncthreads();                 // all block writes done + block-ordered
    __threadfence();                 // agent-scope: publish our global writes
    if (threadIdx.x == 0) {
        __hip_atomic_fetch_add(ctr, 1u, __ATOMIC_ACQ_REL,
                               __HIP_MEMORY_SCOPE_AGENT);
        while (__hip_atomic_load(ctr, __ATOMIC_ACQUIRE,
                                 __HIP_MEMORY_SCOPE_AGENT) < nblk)
            __builtin_amdgcn_s_sleep(1);
    }
    __syncthreads();
    __threadfence();                 // acquire side for all threads
}

// ---------------------------------------------------------------------------
// One kernel, three phases separated by grid barriers:
//  P1: v1/v2/gv projections (per-block 32-position tile, x staged once)
//  P2: per-channel Taylor moments  M_k = sum b^k/k!,  G_k = sum b^k g/k!
//  P3: y = num(a)/den(a) Horner eval, z = kw@y + kb, out = x + z
// ---------------------------------------------------------------------------
__global__ __launch_bounds__(256) void k_fused(
    const float* __restrict__ x,
    const float* __restrict__ tw, const float* __restrict__ tb,
    const float* __restrict__ pw, const float* __restrict__ pb,
    const float* __restrict__ gw, const float* __restrict__ gb,
    const float* __restrict__ kw, const float* __restrict__ kb,
    float* __restrict__ out,
    float* __restrict__ v1, float* __restrict__ v2, float* __restrict__ gv,
    float* __restrict__ coeff, unsigned* __restrict__ bar)
{
    __shared__ float xs[CIN][TILE];            // 8 KB
    __shared__ float wt3[3][CIN][CHALF + 4];   // 27.6 KB, transposed+padded
    __shared__ float bs3[3][CHALF];
    __shared__ float kws[CIN * CHALF];         // 8 KB
    __shared__ float cf[CHALF * 2 * KT];       // 4.25 KB
    __shared__ float ys[CHALF][TILE];          // 4 KB
    __shared__ float red[4][2 * KT];

    const int tid = threadIdx.x;
    const int blk = blockIdx.x;
    const int n0  = blk * TILE;

    // ---- stage x tile, all weights (transposed), biases, kw ----------------
    for (int idx = tid; idx < CIN * TILE; idx += 256) {
        int c = idx >> 5, nn = idx & 31;
        xs[c][nn] = x[c * N + n0 + nn];
    }
    for (int idx = tid; idx < 3 * CHALF * CIN; idx += 256) {
        int p = idx >> 11, rem = idx & 2047;
        int co = rem >> 6, c = rem & 63;
        const float* w = (p == 0) ? tw : (p == 1) ? pw : gw;
        wt3[p][c][co] = w[rem];
    }
    if (tid < 3 * CHALF) {
        int p = tid >> 5, co = tid & 31;
        const float* b = (p == 0) ? tb : (p == 1) ? pb : gb;
        bs3[p][co] = b[co];
    }
    for (int idx = tid; idx < CIN * CHALF; idx += 256)
        kws[idx] = kw[idx];
    __syncthreads();

    // ---- phase 1: three projections for this tile --------------------------
    {
        const int pos = tid & 31;
        const int g   = tid >> 5;              // 0..7 -> co = g*4 + k
        float a0[4], a1[4], a2[4];
        #pragma unroll
        for (int k = 0; k < 4; ++k) { a0[k] = 0.f; a1[k] = 0.f; a2[k] = 0.f; }

        #pragma unroll 4
        for (int c = 0; c < CIN; ++c) {
            float  xv = xs[c][pos];
            float4 w0 = *(const float4*)&wt3[0][c][g * 4];
            float4 w1 = *(const float4*)&wt3[1][c][g * 4];
            float4 w2 = *(const float4*)&wt3[2][c][g * 4];
            a0[0] = fmaf(w0.x, xv, a0[0]); a0[1] = fmaf(w0.y, xv, a0[1]);
            a0[2] = fmaf(w0.z, xv, a0[2]); a0[3] = fmaf(w0.w, xv, a0[3]);
            a1[0] = fmaf(w1.x, xv, a1[0]); a1[1] = fmaf(w1.y, xv, a1[1]);
            a1[2] = fmaf(w1.z, xv, a1[2]); a1[3] = fmaf(w1.w, xv, a1[3]);
            a2[0] = fmaf(w2.x, xv, a2[0]); a2[1] = fmaf(w2.y, xv, a2[1]);
            a2[2] = fmaf(w2.z, xv, a2[2]); a2[3] = fmaf(w2.w, xv, a2[3]);
        }
        #pragma unroll
        for (int k = 0; k < 4; ++k) {
            int co = g * 4 + k;
            int off = co * N + n0 + pos;
            v1[off] = a0[k] + bs3[0][co];
            v2[off] = a1[k] + bs3[1][co];
            gv[off] = a2[k] + bs3[2][co];
        }
    }
    grid_barrier(&bar[0], NBLK);

    // ---- phase 2: per-channel moments (blocks 0..31) -----------------------
    if (blk < CHALF) {
        const int c = blk;
        float den[KT], num[KT];
        #pragma unroll
        for (int k = 0; k < KT; ++k) { den[k] = 0.f; num[k] = 0.f; }

        constexpr float INVK[KT] = {
            0.f, 1.f, 0.5f, 1.f/3.f, 0.25f, 0.2f, 1.f/6.f, 1.f/7.f, 0.125f,
            1.f/9.f, 0.1f, 1.f/11.f, 1.f/12.f, 1.f/13.f, 1.f/14.f, 1.f/15.f,
            0.0625f };

        const float* bp = v2 + c * N;
        const float* gp = gv + c * N;
        for (int j = tid; j < N; j += 256) {
            float b = bp[j], g = gp[j];
            float t = 1.0f;
            den[0] += 1.0f;
            num[0] += g;
            #pragma unroll
            for (int k = 1; k < KT; ++k) {
                t *= b;
                t *= INVK[k];                  // t = b^k / k!
                den[k] += t;
                num[k] = fmaf(t, g, num[k]);
            }
        }
        #pragma unroll
        for (int k = 0; k < KT; ++k) {
            #pragma unroll
            for (int off = 32; off > 0; off >>= 1) {
                den[k] += __shfl_xor(den[k], off);
                num[k] += __shfl_xor(num[k], off);
            }
        }
        const int wave = tid >> 6, lane = tid & 63;
        if (lane == 0) {
            #pragma unroll
            for (int k = 0; k < KT; ++k) {
                red[wave][k]      = den[k];
                red[wave][KT + k] = num[k];
            }
        }
        __syncthreads();
        if (tid < 2 * KT) {
            coeff[c * 2 * KT + tid] =
                red[0][tid] + red[1][tid] + red[2][tid] + red[3][tid];
        }
    }
    grid_barrier(&bar[1], NBLK);

    // ---- phase 3: Horner eval + out-projection + residual ------------------
    for (int idx = tid; idx < CHALF * 2 * KT; idx += 256)
        cf[idx] = coeff[idx];
    __syncthreads();

    {
        const int c = tid >> 3;                // 0..31
        const int l = tid & 7;
        float dc[KT], nc[KT];
        #pragma unroll
        for (int k = 0; k < KT; ++k) {
            dc[k] = cf[c * 2 * KT + k];
            nc[k] = cf[c * 2 * KT + KT + k];
        }
        #pragma unroll
        for (int p = 0; p < 4; ++p) {
            int   ii = l + 8 * p;
            float a  = v1[c * N + n0 + ii];
            float den = dc[KT - 1], num = nc[KT - 1];
            #pragma unroll
            for (int k = KT - 2; k >= 0; --k) {
                den = fmaf(den, a, dc[k]);
                num = fmaf(num, a, nc[k]);
            }
            ys[c][ii] = num / den;
        }
    }
    __syncthreads();

    {
        const int ii = tid & 31;
        const int cg = tid >> 5;               // 0..7 -> co = cg*8 + p
        float yv[CHALF];
        #pragma unroll
        for (int c = 0; c < CHALF; ++c) yv[c] = ys[c][ii];

        #pragma unroll
        for (int p = 0; p < 8; ++p) {
            int   co = cg * 8 + p;
            float z  = kb[co];
            const float4* kr = (const float4*)&kws[co * CHALF];
            #pragma unroll
            for (int c4 = 0; c4 < CHALF / 4; ++c4) {
                float4 kv = kr[c4];
                z = fmaf(kv.x, yv[c4 * 4 + 0], z);
                z = fmaf(kv.y, yv[c4 * 4 + 1], z);
                z = fmaf(kv.z, yv[c4 * 4 + 2], z);
                z = fmaf(kv.w, yv[c4 * 4 + 3], z);
            }
            int off = co * N + n0 + ii;
            out[off] = x[off] + z;
        }
    }
}

// ---------------------------------------------------------------------------
extern "C" void kernel_launch(void* const* d_in, const int* in_sizes, int n_in,
                              void* d_out, int out_size, void* d_ws, size_t ws_size,
                              hipStream_t stream)
{
    const float* x  = (const float*)d_in[0];
    const float* tw = (const float*)d_in[1];
    const float* tb = (const float*)d_in[2];
    const float* pw = (const float*)d_in[3];
    const float* pb = (const float*)d_in[4];
    const float* gw = (const float*)d_in[5];
    const float* gb = (const float*)d_in[6];
    const float* kw = (const float*)d_in[7];
    const float* kb = (const float*)d_in[8];
    float* out = (float*)d_out;

    // workspace layout (floats):
    //   v1 @0, v2 @73728, gv @147456, coeff @221184 (1088),
    //   barrier counters @262144 (2 x u32, zeroed per launch below)
    float*    ws    = (float*)d_ws;
    float*    v1    = ws;
    float*    v2    = ws + 73728;
    float*    gv    = ws + 147456;
    float*    coeff = ws + 221184;
    unsigned* bar   = (unsigned*)(ws + 262144);

    hipMemsetAsync(bar, 0, 2 * sizeof(unsigned), stream);

    k_fused<<<dim3(NBLK), dim3(256), 0, stream>>>(
        x, tw, tb, pw, pb, gw, gb, kw, kb, out, v1, v2, gv, coeff, bar);
}

// Round 6
// 24.184 us; speedup vs baseline: 2.1038x; 2.1038x over previous
//
#include <hip/hip_runtime.h>

#define N      2304        // T*H*W = 4*24*24
#define CIN    64
#define CHALF  32
#define KT     17          // Taylor powers 0..16
#define TILE   32
#define NBLK   (N / TILE)  // 72
#define NCOEF  (2 * KT * CHALF)   // 1088 (den[17][32] then num[17][32])
#define WPAD   36          // weight-tile pad: 16B-aligned float4 rows

__device__ __constant__ float INVF_C[KT] = {
    1.0f, 1.0f, 0.5f, 1.6666667e-1f, 4.1666668e-2f, 8.3333333e-3f,
    1.3888889e-3f, 1.9841270e-4f, 2.4801587e-5f, 2.7557319e-6f,
    2.7557319e-7f, 2.5052108e-8f, 2.0876756e-9f, 1.6059044e-10f,
    1.1470746e-11f, 7.6471637e-13f, 4.7794773e-14f };

// ---------------------------------------------------------------------------
// Kernel A: phi/g projections for a 32-position tile (LDS only) + per-block
// partial moments  den_k = sum_j b^k,  num_k = sum_j b^k g  (1/k! applied in B)
// partial layout: partial[blk][k*32+c] (den), partial[blk][544+k*32+c] (num)
// ---------------------------------------------------------------------------
__global__ __launch_bounds__(256) void k_momA(
    const float* __restrict__ x,
    const float* __restrict__ pw, const float* __restrict__ pb,
    const float* __restrict__ gw, const float* __restrict__ gb,
    float* __restrict__ partial)
{
    __shared__ float xs[CIN][TILE];          // 8 KB
    __shared__ float wt2[2][CIN][WPAD];      // 18 KB (transposed, padded)
    __shared__ float bs2[2][CHALF];
    __shared__ float bl[CHALF][33];          // phi values (b)
    __shared__ float gl[CHALF][33];          // g values

    const int tid = threadIdx.x;
    const int blk = blockIdx.x;
    const int n0  = blk * TILE;

    for (int idx = tid; idx < CIN * TILE; idx += 256) {
        int c = idx >> 5, nn = idx & 31;
        xs[c][nn] = x[c * N + n0 + nn];
    }
    for (int idx = tid; idx < 2 * CHALF * CIN; idx += 256) {
        int p = idx >> 11, rem = idx & 2047;
        int co = rem >> 6, c = rem & 63;
        wt2[p][c][co] = (p ? gw : pw)[rem];  // w is [co][c] row-major
    }
    if (tid < 2 * CHALF) {
        int p = tid >> 5, co = tid & 31;
        bs2[p][co] = (p ? gb : pb)[co];
    }
    __syncthreads();

    // ---- phi & g projections: thread = (pos, 4 output channels) ------------
    {
        const int pos = tid & 31;
        const int g8  = tid >> 5;            // 0..7 -> co = g8*4 + k
        float ab[4] = {0.f,0.f,0.f,0.f}, ag[4] = {0.f,0.f,0.f,0.f};
        #pragma unroll 4
        for (int c = 0; c < CIN; ++c) {
            float  xv = xs[c][pos];
            float4 wb = *(const float4*)&wt2[0][c][g8 * 4];
            float4 wg = *(const float4*)&wt2[1][c][g8 * 4];
            ab[0] = fmaf(wb.x, xv, ab[0]); ab[1] = fmaf(wb.y, xv, ab[1]);
            ab[2] = fmaf(wb.z, xv, ab[2]); ab[3] = fmaf(wb.w, xv, ab[3]);
            ag[0] = fmaf(wg.x, xv, ag[0]); ag[1] = fmaf(wg.y, xv, ag[1]);
            ag[2] = fmaf(wg.z, xv, ag[2]); ag[3] = fmaf(wg.w, xv, ag[3]);
        }
        #pragma unroll
        for (int k = 0; k < 4; ++k) {
            int co = g8 * 4 + k;
            bl[co][pos] = ab[k] + bs2[0][co];
            gl[co][pos] = ag[k] + bs2[1][co];
        }
    }
    __syncthreads();

    // ---- partial moments: thread = (channel c, k-pair {kg+1, kg+9}) --------
    {
        const int c  = tid & 31;
        const int kg = tid >> 5;             // 0..7 (half-wave uniform)
        const int k1 = kg + 1, k2 = kg + 9;  // 1..8 and 9..16
        float d1 = 0.f, n1 = 0.f, d2 = 0.f, n2 = 0.f, n0s = 0.f;
        #pragma unroll 8
        for (int pos = 0; pos < TILE; ++pos) {
            float b  = bl[c][pos];
            float g  = gl[c][pos];
            float b2 = b * b, b4 = b2 * b2, b8 = b4 * b4;
            float p1 = (k1 & 1) ? b : 1.0f;  // b^k1 via bit ladder
            p1 = (k1 & 2) ? p1 * b2 : p1;
            p1 = (k1 & 4) ? p1 * b4 : p1;
            p1 = (k1 & 8) ? p1 * b8 : p1;
            float p2 = p1 * b8;              // b^(k1+8) = b^k2
            d1 += p1; n1 = fmaf(p1, g, n1);
            d2 += p2; n2 = fmaf(p2, g, n2);
            n0s += g;
        }
        float* pp = partial + blk * NCOEF;
        pp[k1 * 32 + c]       = d1;
        pp[544 + k1 * 32 + c] = n1;
        pp[k2 * 32 + c]       = d2;
        pp[544 + k2 * 32 + c] = n2;
        if (kg == 0) {                        // k = 0 moments
            pp[c]       = (float)TILE;        // sum_j b^0 = tile size
            pp[544 + c] = n0s;                // sum_j g
        }
    }
}

// ---------------------------------------------------------------------------
// Kernel B: reduce 72 partials (deterministic order) -> coeffs; theta-proj for
// this tile; Horner num/den eval; out-projection; residual (x from LDS tile).
// ---------------------------------------------------------------------------
__global__ __launch_bounds__(256) void k_evalB(
    const float* __restrict__ x,
    const float* __restrict__ tw, const float* __restrict__ tb,
    const float* __restrict__ kw, const float* __restrict__ kb,
    const float* __restrict__ partial,
    float* __restrict__ out)
{
    __shared__ float xs[CIN][TILE];          // 8 KB
    __shared__ float wtt[CIN][WPAD];         // 9 KB theta, transposed
    __shared__ float kws[CIN * CHALF];       // 8 KB
    __shared__ float tbs[CHALF];
    __shared__ float cfl[NCOEF];             // 4.25 KB summed coeffs
    __shared__ float al[CHALF][40];          // theta-proj values (bank-safe)
    __shared__ float ys[CHALF][33];

    const int tid = threadIdx.x;
    const int n0  = blockIdx.x * TILE;

    for (int idx = tid; idx < CIN * TILE; idx += 256) {
        int c = idx >> 5, nn = idx & 31;
        xs[c][nn] = x[c * N + n0 + nn];
    }
    for (int idx = tid; idx < CHALF * CIN; idx += 256) {
        int co = idx >> 6, c = idx & 63;
        wtt[c][co] = tw[idx];
    }
    for (int idx = tid; idx < CIN * CHALF; idx += 256)
        kws[idx] = kw[idx];
    if (tid < CHALF) tbs[tid] = tb[tid];

    // ---- reduce partials over 72 blocks (float4 columns, fixed order) ------
    for (int t = tid; t < NCOEF / 4; t += 256) {     // 272 float4 columns
        float4 v = make_float4(0.f, 0.f, 0.f, 0.f);
        for (int s = 0; s < NBLK; ++s) {
            float4 p = *(const float4*)&partial[s * NCOEF + t * 4];
            v.x += p.x; v.y += p.y; v.z += p.z; v.w += p.w;
        }
        int idx = t * 4;
        int k = (idx < 544) ? (idx >> 5) : ((idx - 544) >> 5);
        float f = INVF_C[k];                 // fold 1/k! here
        v.x *= f; v.y *= f; v.z *= f; v.w *= f;
        *(float4*)&cfl[idx] = v;
    }
    __syncthreads();

    // ---- theta projection: a[c][pos] ---------------------------------------
    {
        const int pos = tid & 31;
        const int g8  = tid >> 5;
        float aa[4] = {0.f,0.f,0.f,0.f};
        #pragma unroll 4
        for (int c = 0; c < CIN; ++c) {
            float  xv = xs[c][pos];
            float4 wv = *(const float4*)&wtt[c][g8 * 4];
            aa[0] = fmaf(wv.x, xv, aa[0]); aa[1] = fmaf(wv.y, xv, aa[1]);
            aa[2] = fmaf(wv.z, xv, aa[2]); aa[3] = fmaf(wv.w, xv, aa[3]);
        }
        #pragma unroll
        for (int k = 0; k < 4; ++k) {
            int co = g8 * 4 + k;
            al[co][pos] = aa[k] + tbs[co];
        }
    }
    __syncthreads();

    // ---- Horner eval: y = num(a)/den(a) ------------------------------------
    {
        const int c = tid >> 3;              // 0..31
        const int l = tid & 7;
        float dc[KT], nc[KT];
        #pragma unroll
        for (int k = 0; k < KT; ++k) {
            dc[k] = cfl[k * 32 + c];
            nc[k] = cfl[544 + k * 32 + c];
        }
        #pragma unroll
        for (int p = 0; p < 4; ++p) {
            int   ii = l + 8 * p;
            float a  = al[c][ii];
            float den = dc[KT - 1], num = nc[KT - 1];
            #pragma unroll
            for (int k = KT - 2; k >= 0; --k) {
                den = fmaf(den, a, dc[k]);
                num = fmaf(num, a, nc[k]);
            }
            ys[c][ii] = num / den;
        }
    }
    __syncthreads();

    // ---- out-projection + residual (x re-used from LDS) --------------------
    {
        const int ii = tid & 31;
        const int cg = tid >> 5;             // 0..7 -> co = cg*8 + p
        float yv[CHALF];
        #pragma unroll
        for (int c = 0; c < CHALF; ++c) yv[c] = ys[c][ii];

        #pragma unroll
        for (int p = 0; p < 8; ++p) {
            int   co = cg * 8 + p;
            float z  = kb[co];
            const float4* kr = (const float4*)&kws[co * CHALF];
            #pragma unroll
            for (int c4 = 0; c4 < CHALF / 4; ++c4) {
                float4 kv = kr[c4];
                z = fmaf(kv.x, yv[c4 * 4 + 0], z);
                z = fmaf(kv.y, yv[c4 * 4 + 1], z);
                z = fmaf(kv.z, yv[c4 * 4 + 2], z);
                z = fmaf(kv.w, yv[c4 * 4 + 3], z);
            }
            out[co * N + n0 + ii] = xs[co][ii] + z;
        }
    }
}

// ---------------------------------------------------------------------------
extern "C" void kernel_launch(void* const* d_in, const int* in_sizes, int n_in,
                              void* d_out, int out_size, void* d_ws, size_t ws_size,
                              hipStream_t stream)
{
    const float* x  = (const float*)d_in[0];
    const float* tw = (const float*)d_in[1];
    const float* tb = (const float*)d_in[2];
    const float* pw = (const float*)d_in[3];
    const float* pb = (const float*)d_in[4];
    const float* gw = (const float*)d_in[5];
    const float* gb = (const float*)d_in[6];
    const float* kw = (const float*)d_in[7];
    const float* kb = (const float*)d_in[8];
    float* out = (float*)d_out;

    // workspace: partial[72][1088] floats (fully rewritten every launch)
    float* partial = (float*)d_ws;

    k_momA<<<dim3(NBLK), dim3(256), 0, stream>>>(
        x, pw, pb, gw, gb, partial);

    k_evalB<<<dim3(NBLK), dim3(256), 0, stream>>>(
        x, tw, tb, kw, kb, partial, out);
}

// Round 7
// 22.836 us; speedup vs baseline: 2.2279x; 1.0590x over previous
//
#include <hip/hip_runtime.h>

#define N      2304        // T*H*W = 4*24*24
#define CIN    64
#define CHALF  32
#define KT     17          // Taylor powers 0..16
#define TILE   32
#define NBLK   (N / TILE)  // 72
#define NCOEF  (2 * KT * CHALF)   // 1088
#define NCOL   (NCOEF / 4)        // 272

__device__ __constant__ float INVF_C[KT] = {
    1.0f, 1.0f, 0.5f, 1.6666667e-1f, 4.1666668e-2f, 8.3333333e-3f,
    1.3888889e-3f, 1.9841270e-4f, 2.4801587e-5f, 2.7557319e-6f,
    2.7557319e-7f, 2.5052108e-8f, 2.0876756e-9f, 1.6059044e-10f,
    1.1470746e-11f, 7.6471637e-13f, 4.7794773e-14f };

// ---------------------------------------------------------------------------
// Kernel A: theta/phi/g projections (register-blocked 4x4, one wave per
// projection) + per-block Taylor moment partials.
//   v1 (theta) -> global; phi/g stay in LDS; partial[blk][1088] -> global.
// ---------------------------------------------------------------------------
__global__ __launch_bounds__(256) void k_momA(
    const float* __restrict__ x,
    const float* __restrict__ tw, const float* __restrict__ tb,
    const float* __restrict__ pw, const float* __restrict__ pb,
    const float* __restrict__ gw, const float* __restrict__ gb,
    float* __restrict__ v1, float* __restrict__ partial)
{
    __shared__ float xs[CIN][TILE];        // 8 KB, rows 128 B
    __shared__ float wt3[3][CIN][36];      // 27.6 KB transposed, 16B-aligned rows
    __shared__ float bs3[3][CHALF];
    __shared__ float bl[CHALF][36];        // phi values
    __shared__ float gl[CHALF][36];        // g values

    const int tid = threadIdx.x;
    const int blk = blockIdx.x;
    const int n0  = blk * TILE;

    for (int idx = tid; idx < CIN * TILE; idx += 256) {
        int c = idx >> 5, nn = idx & 31;
        xs[c][nn] = x[c * N + n0 + nn];
    }
    for (int idx = tid; idx < 3 * CHALF * CIN; idx += 256) {
        int p = idx >> 11, rem = idx & 2047;
        int co = rem >> 6, c = rem & 63;
        const float* w = (p == 0) ? tw : (p == 1) ? pw : gw;
        wt3[p][c][co] = w[rem];            // w is [co][c] row-major
    }
    if (tid < 3 * CHALF) {
        int p = tid >> 5, co = tid & 31;
        const float* b = (p == 0) ? tb : (p == 1) ? pb : gb;
        bs3[p][co] = b[co];
    }
    __syncthreads();

    // ---- projections: thread = (pos-quad, co-quad, proj); wave = proj ------
    if (tid < 192) {
        const int pog = tid & 7;           // pos quad
        const int cog = (tid >> 3) & 7;    // co quad
        const int pj  = tid >> 6;          // 0=theta 1=phi 2=g (wave-uniform)

        float acc[4][4];                   // [co][pos]
        #pragma unroll
        for (int i = 0; i < 4; ++i)
            #pragma unroll
            for (int j = 0; j < 4; ++j) acc[i][j] = 0.f;

        #pragma unroll 4
        for (int c = 0; c < CIN; ++c) {
            float4 xv = *(const float4*)&xs[c][pog * 4];
            float4 wv = *(const float4*)&wt3[pj][c][cog * 4];
            acc[0][0]=fmaf(wv.x,xv.x,acc[0][0]); acc[0][1]=fmaf(wv.x,xv.y,acc[0][1]);
            acc[0][2]=fmaf(wv.x,xv.z,acc[0][2]); acc[0][3]=fmaf(wv.x,xv.w,acc[0][3]);
            acc[1][0]=fmaf(wv.y,xv.x,acc[1][0]); acc[1][1]=fmaf(wv.y,xv.y,acc[1][1]);
            acc[1][2]=fmaf(wv.y,xv.z,acc[1][2]); acc[1][3]=fmaf(wv.y,xv.w,acc[1][3]);
            acc[2][0]=fmaf(wv.z,xv.x,acc[2][0]); acc[2][1]=fmaf(wv.z,xv.y,acc[2][1]);
            acc[2][2]=fmaf(wv.z,xv.z,acc[2][2]); acc[2][3]=fmaf(wv.z,xv.w,acc[2][3]);
            acc[3][0]=fmaf(wv.w,xv.x,acc[3][0]); acc[3][1]=fmaf(wv.w,xv.y,acc[3][1]);
            acc[3][2]=fmaf(wv.w,xv.z,acc[3][2]); acc[3][3]=fmaf(wv.w,xv.w,acc[3][3]);
        }
        #pragma unroll
        for (int i = 0; i < 4; ++i) {
            int   co = cog * 4 + i;
            float bb = bs3[pj][co];
            float4 r = make_float4(acc[i][0] + bb, acc[i][1] + bb,
                                   acc[i][2] + bb, acc[i][3] + bb);
            if (pj == 0) {
                *(float4*)&v1[co * N + n0 + pog * 4] = r;
            } else if (pj == 1) {
                *(float4*)&bl[co][pog * 4] = r;
            } else {
                *(float4*)&gl[co][pog * 4] = r;
            }
        }
    }
    __syncthreads();

    // ---- moments: thread = (channel c, k-pair {kg+1, kg+9}), float4 pos ----
    {
        const int c  = tid & 31;
        const int kg = tid >> 5;           // 0..7
        const int k1 = kg + 1;             // 1..8 ; k2 = k1 + 8
        float d1 = 0.f, n1 = 0.f, d2 = 0.f, n2 = 0.f, n0s = 0.f;
        #pragma unroll
        for (int pq = 0; pq < 8; ++pq) {
            float4 b4 = *(const float4*)&bl[c][pq * 4];
            float4 g4 = *(const float4*)&gl[c][pq * 4];
            #pragma unroll
            for (int e = 0; e < 4; ++e) {
                float b = (e == 0) ? b4.x : (e == 1) ? b4.y : (e == 2) ? b4.z : b4.w;
                float g = (e == 0) ? g4.x : (e == 1) ? g4.y : (e == 2) ? g4.z : g4.w;
                float b2 = b * b, b4v = b2 * b2, b8 = b4v * b4v;
                float p1 = (k1 & 1) ? b : 1.0f;
                p1 = (k1 & 2) ? p1 * b2  : p1;
                p1 = (k1 & 4) ? p1 * b4v : p1;
                p1 = (k1 & 8) ? p1 * b8  : p1;   // b^k1
                float p2 = p1 * b8;              // b^(k1+8)
                d1 += p1; n1 = fmaf(p1, g, n1);
                d2 += p2; n2 = fmaf(p2, g, n2);
                n0s += g;
            }
        }
        float* pp = partial + blk * NCOEF;
        pp[k1 * 32 + c]             = d1;
        pp[544 + k1 * 32 + c]       = n1;
        pp[(k1 + 8) * 32 + c]       = d2;
        pp[544 + (k1 + 8) * 32 + c] = n2;
        if (kg == 0) {
            pp[c]       = (float)TILE;     // k=0 den
            pp[544 + c] = n0s;             // k=0 num
        }
    }
}

// ---------------------------------------------------------------------------
// Kernel B: reduce 72 partials -> coeffs (1/k! folded); Horner eval of
// y = num(a)/den(a) from v1; out-projection (register-blocked, c-split) +
// residual with x read direct from global.
// ---------------------------------------------------------------------------
__global__ __launch_bounds__(256) void k_evalB(
    const float* __restrict__ x,
    const float* __restrict__ kw, const float* __restrict__ kb,
    const float* __restrict__ v1, const float* __restrict__ partial,
    float* __restrict__ out)
{
    __shared__ float kwt[CHALF][68];       // transposed kw [c][co], 272B rows
    __shared__ float cfl[NCOEF];           // 4.25 KB
    __shared__ float ys[CHALF][36];        // 4.5 KB
    __shared__ float kbs[CIN];
    __shared__ float zred[8][16][16];      // 16 KB c-split combine buffer

    const int tid = threadIdx.x;
    const int n0  = blockIdx.x * TILE;

    for (int idx = tid; idx < CIN * CHALF; idx += 256) {
        int co = idx >> 5, c = idx & 31;
        kwt[c][co] = kw[idx];              // kw is [co=64][c=32] row-major
    }
    if (tid < CIN) kbs[tid] = kb[tid];

    // ---- reduce partials (deterministic order), fold 1/k! ------------------
    for (int col = tid; col < NCOL; col += 256) {
        float4 v = make_float4(0.f, 0.f, 0.f, 0.f);
        for (int s = 0; s < NBLK; ++s) {
            float4 p = *(const float4*)&partial[s * NCOEF + col * 4];
            v.x += p.x; v.y += p.y; v.z += p.z; v.w += p.w;
        }
        int idx = col * 4;
        int k = (idx < 544) ? (idx >> 5) : ((idx - 544) >> 5);
        float f = INVF_C[k];
        v.x *= f; v.y *= f; v.z *= f; v.w *= f;
        *(float4*)&cfl[idx] = v;
    }
    __syncthreads();

    // ---- Horner: thread = (c, pos-quad) ------------------------------------
    {
        const int c  = tid >> 3;
        const int pq = tid & 7;
        float dc[KT], nc[KT];
        #pragma unroll
        for (int k = 0; k < KT; ++k) {
            dc[k] = cfl[k * 32 + c];
            nc[k] = cfl[544 + k * 32 + c];
        }
        float4 a4 = *(const float4*)&v1[c * N + n0 + pq * 4];
        float4 r;
        #pragma unroll
        for (int e = 0; e < 4; ++e) {
            float a = (e == 0) ? a4.x : (e == 1) ? a4.y : (e == 2) ? a4.z : a4.w;
            float den = dc[KT - 1], num = nc[KT - 1];
            #pragma unroll
            for (int k = KT - 2; k >= 0; --k) {
                den = fmaf(den, a, dc[k]);
                num = fmaf(num, a, nc[k]);
            }
            float yv = num / den;
            if (e == 0) r.x = yv; else if (e == 1) r.y = yv;
            else if (e == 2) r.z = yv; else r.w = yv;
        }
        *(float4*)&ys[c][pq * 4] = r;
    }
    __syncthreads();

    // ---- out-projection: thread = (pos-quad, co-quad, c-half) --------------
    {
        const int posq = tid & 7;
        const int coq  = (tid >> 3) & 15;
        const int ch   = tid >> 7;         // 0 or 1
        float acc[4][4];                   // [co][pos]
        #pragma unroll
        for (int i = 0; i < 4; ++i)
            #pragma unroll
            for (int j = 0; j < 4; ++j) acc[i][j] = 0.f;

        #pragma unroll 4
        for (int i = 0; i < 16; ++i) {
            int c = ch * 16 + i;
            float4 yv = *(const float4*)&ys[c][posq * 4];
            float4 wv = *(const float4*)&kwt[c][coq * 4];
            acc[0][0]=fmaf(wv.x,yv.x,acc[0][0]); acc[0][1]=fmaf(wv.x,yv.y,acc[0][1]);
            acc[0][2]=fmaf(wv.x,yv.z,acc[0][2]); acc[0][3]=fmaf(wv.x,yv.w,acc[0][3]);
            acc[1][0]=fmaf(wv.y,yv.x,acc[1][0]); acc[1][1]=fmaf(wv.y,yv.y,acc[1][1]);
            acc[1][2]=fmaf(wv.y,yv.z,acc[1][2]); acc[1][3]=fmaf(wv.y,yv.w,acc[1][3]);
            acc[2][0]=fmaf(wv.z,yv.x,acc[2][0]); acc[2][1]=fmaf(wv.z,yv.y,acc[2][1]);
            acc[2][2]=fmaf(wv.z,yv.z,acc[2][2]); acc[2][3]=fmaf(wv.z,yv.w,acc[2][3]);
            acc[3][0]=fmaf(wv.w,yv.x,acc[3][0]); acc[3][1]=fmaf(wv.w,yv.y,acc[3][1]);
            acc[3][2]=fmaf(wv.w,yv.z,acc[3][2]); acc[3][3]=fmaf(wv.w,yv.w,acc[3][3]);
        }

        if (ch == 1) {
            #pragma unroll
            for (int i = 0; i < 4; ++i)
                *(float4*)&zred[posq][coq][i * 4] =
                    make_float4(acc[i][0], acc[i][1], acc[i][2], acc[i][3]);
        }
        __syncthreads();
        if (ch == 0) {
            #pragma unroll
            for (int i = 0; i < 4; ++i) {
                int    co  = coq * 4 + i;
                float  kbv = kbs[co];
                float4 zo  = *(const float4*)&zred[posq][coq][i * 4];
                float4 xv  = *(const float4*)&x[co * N + n0 + posq * 4];
                float4 o;
                o.x = xv.x + acc[i][0] + zo.x + kbv;
                o.y = xv.y + acc[i][1] + zo.y + kbv;
                o.z = xv.z + acc[i][2] + zo.z + kbv;
                o.w = xv.w + acc[i][3] + zo.w + kbv;
                *(float4*)&out[co * N + n0 + posq * 4] = o;
            }
        }
    }
}

// ---------------------------------------------------------------------------
extern "C" void kernel_launch(void* const* d_in, const int* in_sizes, int n_in,
                              void* d_out, int out_size, void* d_ws, size_t ws_size,
                              hipStream_t stream)
{
    const float* x  = (const float*)d_in[0];
    const float* tw = (const float*)d_in[1];
    const float* tb = (const float*)d_in[2];
    const float* pw = (const float*)d_in[3];
    const float* pb = (const float*)d_in[4];
    const float* gw = (const float*)d_in[5];
    const float* gb = (const float*)d_in[6];
    const float* kw = (const float*)d_in[7];
    const float* kb = (const float*)d_in[8];
    float* out = (float*)d_out;

    // workspace (floats): v1 @0 (73728), partial[72][1088] @73728
    float* ws      = (float*)d_ws;
    float* v1      = ws;
    float* partial = ws + 73728;

    k_momA<<<dim3(NBLK), dim3(256), 0, stream>>>(
        x, tw, tb, pw, pb, gw, gb, v1, partial);

    k_evalB<<<dim3(NBLK), dim3(256), 0, stream>>>(
        x, kw, kb, v1, partial, out);
}

// Round 8
// 20.815 us; speedup vs baseline: 2.4442x; 1.0971x over previous
//
#include <hip/hip_runtime.h>

#define N      2304        // T*H*W = 4*24*24
#define CIN    64
#define CHALF  32
#define KT     17          // Taylor powers 0..16
#define TILE   32
#define NBLK   (N / TILE)  // 72
#define NCOEF  (2 * KT * CHALF)   // 1088
#define NCOL   (NCOEF / 4)        // 272

__device__ __constant__ float INVF_C[KT] = {
    1.0f, 1.0f, 0.5f, 1.6666667e-1f, 4.1666668e-2f, 8.3333333e-3f,
    1.3888889e-3f, 1.9841270e-4f, 2.4801587e-5f, 2.7557319e-6f,
    2.7557319e-7f, 2.5052108e-8f, 2.0876756e-9f, 1.6059044e-10f,
    1.1470746e-11f, 7.6471637e-13f, 4.7794773e-14f };

// ---------------------------------------------------------------------------
// K1: theta/phi/g projections (register-blocked 4x4, one wave per projection)
// + per-block Taylor moment partials.
//   v1 (theta) -> global; phi/g stay in LDS; partial[blk][1088] -> global.
// ---------------------------------------------------------------------------
__global__ __launch_bounds__(256) void k_momA(
    const float* __restrict__ x,
    const float* __restrict__ tw, const float* __restrict__ tb,
    const float* __restrict__ pw, const float* __restrict__ pb,
    const float* __restrict__ gw, const float* __restrict__ gb,
    float* __restrict__ v1, float* __restrict__ partial)
{
    __shared__ float xs[CIN][TILE];        // 8 KB, rows 128 B
    __shared__ float wt3[3][CIN][36];      // 27.6 KB transposed, 16B-aligned rows
    __shared__ float bs3[3][CHALF];
    __shared__ float bl[CHALF][36];        // phi values
    __shared__ float gl[CHALF][36];        // g values

    const int tid = threadIdx.x;
    const int blk = blockIdx.x;
    const int n0  = blk * TILE;

    for (int idx = tid; idx < CIN * TILE; idx += 256) {
        int c = idx >> 5, nn = idx & 31;
        xs[c][nn] = x[c * N + n0 + nn];
    }
    for (int idx = tid; idx < 3 * CHALF * CIN; idx += 256) {
        int p = idx >> 11, rem = idx & 2047;
        int co = rem >> 6, c = rem & 63;
        const float* w = (p == 0) ? tw : (p == 1) ? pw : gw;
        wt3[p][c][co] = w[rem];            // w is [co][c] row-major
    }
    if (tid < 3 * CHALF) {
        int p = tid >> 5, co = tid & 31;
        const float* b = (p == 0) ? tb : (p == 1) ? pb : gb;
        bs3[p][co] = b[co];
    }
    __syncthreads();

    // ---- projections: thread = (pos-quad, co-quad, proj); wave = proj ------
    if (tid < 192) {
        const int pog = tid & 7;           // pos quad
        const int cog = (tid >> 3) & 7;    // co quad
        const int pj  = tid >> 6;          // 0=theta 1=phi 2=g (wave-uniform)

        float acc[4][4];                   // [co][pos]
        #pragma unroll
        for (int i = 0; i < 4; ++i)
            #pragma unroll
            for (int j = 0; j < 4; ++j) acc[i][j] = 0.f;

        #pragma unroll 4
        for (int c = 0; c < CIN; ++c) {
            float4 xv = *(const float4*)&xs[c][pog * 4];
            float4 wv = *(const float4*)&wt3[pj][c][cog * 4];
            acc[0][0]=fmaf(wv.x,xv.x,acc[0][0]); acc[0][1]=fmaf(wv.x,xv.y,acc[0][1]);
            acc[0][2]=fmaf(wv.x,xv.z,acc[0][2]); acc[0][3]=fmaf(wv.x,xv.w,acc[0][3]);
            acc[1][0]=fmaf(wv.y,xv.x,acc[1][0]); acc[1][1]=fmaf(wv.y,xv.y,acc[1][1]);
            acc[1][2]=fmaf(wv.y,xv.z,acc[1][2]); acc[1][3]=fmaf(wv.y,xv.w,acc[1][3]);
            acc[2][0]=fmaf(wv.z,xv.x,acc[2][0]); acc[2][1]=fmaf(wv.z,xv.y,acc[2][1]);
            acc[2][2]=fmaf(wv.z,xv.z,acc[2][2]); acc[2][3]=fmaf(wv.z,xv.w,acc[2][3]);
            acc[3][0]=fmaf(wv.w,xv.x,acc[3][0]); acc[3][1]=fmaf(wv.w,xv.y,acc[3][1]);
            acc[3][2]=fmaf(wv.w,xv.z,acc[3][2]); acc[3][3]=fmaf(wv.w,xv.w,acc[3][3]);
        }
        #pragma unroll
        for (int i = 0; i < 4; ++i) {
            int   co = cog * 4 + i;
            float bb = bs3[pj][co];
            float4 r = make_float4(acc[i][0] + bb, acc[i][1] + bb,
                                   acc[i][2] + bb, acc[i][3] + bb);
            if (pj == 0) {
                *(float4*)&v1[co * N + n0 + pog * 4] = r;
            } else if (pj == 1) {
                *(float4*)&bl[co][pog * 4] = r;
            } else {
                *(float4*)&gl[co][pog * 4] = r;
            }
        }
    }
    __syncthreads();

    // ---- moments: thread = (channel c, k-pair {kg+1, kg+9}), float4 pos ----
    {
        const int c  = tid & 31;
        const int kg = tid >> 5;           // 0..7
        const int k1 = kg + 1;             // 1..8 ; k2 = k1 + 8
        float d1 = 0.f, n1 = 0.f, d2 = 0.f, n2 = 0.f, n0s = 0.f;
        #pragma unroll
        for (int pq = 0; pq < 8; ++pq) {
            float4 b4 = *(const float4*)&bl[c][pq * 4];
            float4 g4 = *(const float4*)&gl[c][pq * 4];
            #pragma unroll
            for (int e = 0; e < 4; ++e) {
                float b = (e == 0) ? b4.x : (e == 1) ? b4.y : (e == 2) ? b4.z : b4.w;
                float g = (e == 0) ? g4.x : (e == 1) ? g4.y : (e == 2) ? g4.z : g4.w;
                float b2 = b * b, b4v = b2 * b2, b8 = b4v * b4v;
                float p1 = (k1 & 1) ? b : 1.0f;
                p1 = (k1 & 2) ? p1 * b2  : p1;
                p1 = (k1 & 4) ? p1 * b4v : p1;
                p1 = (k1 & 8) ? p1 * b8  : p1;   // b^k1
                float p2 = p1 * b8;              // b^(k1+8)
                d1 += p1; n1 = fmaf(p1, g, n1);
                d2 += p2; n2 = fmaf(p2, g, n2);
                n0s += g;
            }
        }
        float* pp = partial + blk * NCOEF;
        pp[k1 * 32 + c]             = d1;
        pp[544 + k1 * 32 + c]       = n1;
        pp[(k1 + 8) * 32 + c]       = d2;
        pp[544 + (k1 + 8) * 32 + c] = n2;
        if (kg == 0) {
            pp[c]       = (float)TILE;     // k=0 den
            pp[544 + c] = n0s;             // k=0 num
        }
    }
}

// ---------------------------------------------------------------------------
// K2: reduce partial[72][1088] -> coeff[1088] (1/k! folded). Runs ONCE.
// Thread e sums column e over the 72 rows; lane-consecutive e => coalesced.
// ---------------------------------------------------------------------------
__global__ __launch_bounds__(256) void k_reduce(
    const float* __restrict__ partial, float* __restrict__ coeff)
{
    const int e = blockIdx.x * 256 + threadIdx.x;
    if (e >= NCOEF) return;
    float acc = 0.f;
    #pragma unroll 8
    for (int s = 0; s < NBLK; ++s)
        acc += partial[s * NCOEF + e];
    const int k = (e < 544) ? (e >> 5) : ((e - 544) >> 5);
    coeff[e] = acc * INVF_C[k];
}

// ---------------------------------------------------------------------------
// K3: Horner eval of y = num(a)/den(a) from v1 + coeff; out-projection
// (register-blocked, c-split) + residual with x read direct from global.
// ---------------------------------------------------------------------------
__global__ __launch_bounds__(256) void k_evalB(
    const float* __restrict__ x,
    const float* __restrict__ kw, const float* __restrict__ kb,
    const float* __restrict__ v1, const float* __restrict__ coeff,
    float* __restrict__ out)
{
    __shared__ float kwt[CHALF][68];       // transposed kw [c][co], 272B rows
    __shared__ __align__(16) float cfl[NCOEF];   // 4.25 KB
    __shared__ float ys[CHALF][36];        // 4.5 KB
    __shared__ float kbs[CIN];
    __shared__ float zred[8][16][16];      // 16 KB c-split combine buffer

    const int tid = threadIdx.x;
    const int n0  = blockIdx.x * TILE;

    for (int idx = tid; idx < CIN * CHALF; idx += 256) {
        int co = idx >> 5, c = idx & 31;
        kwt[c][co] = kw[idx];              // kw is [co=64][c=32] row-major
    }
    if (tid < CIN) kbs[tid] = kb[tid];
    for (int col = tid; col < NCOL; col += 256)
        *(float4*)&cfl[col * 4] = *(const float4*)&coeff[col * 4];
    __syncthreads();

    // ---- Horner: thread = (c, pos-quad) ------------------------------------
    {
        const int c  = tid >> 3;
        const int pq = tid & 7;
        float dc[KT], nc[KT];
        #pragma unroll
        for (int k = 0; k < KT; ++k) {
            dc[k] = cfl[k * 32 + c];
            nc[k] = cfl[544 + k * 32 + c];
        }
        float4 a4 = *(const float4*)&v1[c * N + n0 + pq * 4];
        float4 r;
        #pragma unroll
        for (int e = 0; e < 4; ++e) {
            float a = (e == 0) ? a4.x : (e == 1) ? a4.y : (e == 2) ? a4.z : a4.w;
            float den = dc[KT - 1], num = nc[KT - 1];
            #pragma unroll
            for (int k = KT - 2; k >= 0; --k) {
                den = fmaf(den, a, dc[k]);
                num = fmaf(num, a, nc[k]);
            }
            float yv = num / den;
            if (e == 0) r.x = yv; else if (e == 1) r.y = yv;
            else if (e == 2) r.z = yv; else r.w = yv;
        }
        *(float4*)&ys[c][pq * 4] = r;
    }
    __syncthreads();

    // ---- out-projection: thread = (pos-quad, co-quad, c-half) --------------
    {
        const int posq = tid & 7;
        const int coq  = (tid >> 3) & 15;
        const int ch   = tid >> 7;         // 0 or 1
        float acc[4][4];                   // [co][pos]
        #pragma unroll
        for (int i = 0; i < 4; ++i)
            #pragma unroll
            for (int j = 0; j < 4; ++j) acc[i][j] = 0.f;

        #pragma unroll 4
        for (int i = 0; i < 16; ++i) {
            int c = ch * 16 + i;
            float4 yv = *(const float4*)&ys[c][posq * 4];
            float4 wv = *(const float4*)&kwt[c][coq * 4];
            acc[0][0]=fmaf(wv.x,yv.x,acc[0][0]); acc[0][1]=fmaf(wv.x,yv.y,acc[0][1]);
            acc[0][2]=fmaf(wv.x,yv.z,acc[0][2]); acc[0][3]=fmaf(wv.x,yv.w,acc[0][3]);
            acc[1][0]=fmaf(wv.y,yv.x,acc[1][0]); acc[1][1]=fmaf(wv.y,yv.y,acc[1][1]);
            acc[1][2]=fmaf(wv.y,yv.z,acc[1][2]); acc[1][3]=fmaf(wv.y,yv.w,acc[1][3]);
            acc[2][0]=fmaf(wv.z,yv.x,acc[2][0]); acc[2][1]=fmaf(wv.z,yv.y,acc[2][1]);
            acc[2][2]=fmaf(wv.z,yv.z,acc[2][2]); acc[2][3]=fmaf(wv.z,yv.w,acc[2][3]);
            acc[3][0]=fmaf(wv.w,yv.x,acc[3][0]); acc[3][1]=fmaf(wv.w,yv.y,acc[3][1]);
            acc[3][2]=fmaf(wv.w,yv.z,acc[3][2]); acc[3][3]=fmaf(wv.w,yv.w,acc[3][3]);
        }

        if (ch == 1) {
            #pragma unroll
            for (int i = 0; i < 4; ++i)
                *(float4*)&zred[posq][coq][i * 4] =
                    make_float4(acc[i][0], acc[i][1], acc[i][2], acc[i][3]);
        }
        __syncthreads();
        if (ch == 0) {
            #pragma unroll
            for (int i = 0; i < 4; ++i) {
                int    co  = coq * 4 + i;
                float  kbv = kbs[co];
                float4 zo  = *(const float4*)&zred[posq][coq][i * 4];
                float4 xv  = *(const float4*)&x[co * N + n0 + posq * 4];
                float4 o;
                o.x = xv.x + acc[i][0] + zo.x + kbv;
                o.y = xv.y + acc[i][1] + zo.y + kbv;
                o.z = xv.z + acc[i][2] + zo.z + kbv;
                o.w = xv.w + acc[i][3] + zo.w + kbv;
                *(float4*)&out[co * N + n0 + posq * 4] = o;
            }
        }
    }
}

// ---------------------------------------------------------------------------
extern "C" void kernel_launch(void* const* d_in, const int* in_sizes, int n_in,
                              void* d_out, int out_size, void* d_ws, size_t ws_size,
                              hipStream_t stream)
{
    const float* x  = (const float*)d_in[0];
    const float* tw = (const float*)d_in[1];
    const float* tb = (const float*)d_in[2];
    const float* pw = (const float*)d_in[3];
    const float* pb = (const float*)d_in[4];
    const float* gw = (const float*)d_in[5];
    const float* gb = (const float*)d_in[6];
    const float* kw = (const float*)d_in[7];
    const float* kb = (const float*)d_in[8];
    float* out = (float*)d_out;

    // workspace (floats): v1 @0 (73728), partial[72][1088] @73728 (78336),
    //                     coeff[1088] @152064
    float* ws      = (float*)d_ws;
    float* v1      = ws;
    float* partial = ws + 73728;
    float* coeff   = ws + 152064;

    k_momA<<<dim3(NBLK), dim3(256), 0, stream>>>(
        x, tw, tb, pw, pb, gw, gb, v1, partial);

    k_reduce<<<dim3((NCOEF + 255) / 256), dim3(256), 0, stream>>>(
        partial, coeff);

    k_evalB<<<dim3(NBLK), dim3(256), 0, stream>>>(
        x, kw, kb, v1, coeff, out);
}

// Round 9
// 20.758 us; speedup vs baseline: 2.4509x; 1.0027x over previous
//
#include <hip/hip_runtime.h>

#define N      2304        // T*H*W = 4*24*24
#define CIN    64
#define CHALF  32
#define KT     17          // Taylor powers 0..16
#define CSTRIDE 40         // coeff row stride: [c][2][20]
#define NCOEF_T (CHALF * CSTRIDE)   // 1280 floats

__device__ __constant__ float INVF_C[KT] = {
    1.0f, 1.0f, 0.5f, 1.6666667e-1f, 4.1666668e-2f, 8.3333333e-3f,
    1.3888889e-3f, 1.9841270e-4f, 2.4801587e-5f, 2.7557319e-6f,
    2.7557319e-7f, 2.5052108e-8f, 2.0876756e-9f, 1.6059044e-10f,
    1.1470746e-11f, 7.6471637e-13f, 4.7794773e-14f };

// ---------------------------------------------------------------------------
// K1: projections, zero LDS. grid (36 tiles, 24 tasks), block = 1 wave (64).
// task = (pj, coq): pj in {theta,phi,g}, coq = 4-channel quad. Lane = position.
// x column lives in 64 VGPRs; weight rows are wave-uniform -> scalar loads.
// ---------------------------------------------------------------------------
__global__ __launch_bounds__(64) void k_proj(
    const float* __restrict__ x,
    const float* __restrict__ tw, const float* __restrict__ tb,
    const float* __restrict__ pw, const float* __restrict__ pb,
    const float* __restrict__ gw, const float* __restrict__ gb,
    float* __restrict__ v1, float* __restrict__ bl, float* __restrict__ gl)
{
    const int lane = threadIdx.x;          // position within 64-pos tile
    const int n0   = blockIdx.x * 64;
    const int task = blockIdx.y;           // 0..23
    const int pj   = task >> 3;            // 0,1,2
    const int coq  = task & 7;             // 0..7

    const float* w = (pj == 0) ? tw : (pj == 1) ? pw : gw;
    const float* b = (pj == 0) ? tb : (pj == 1) ? pb : gb;
    float*       o = (pj == 0) ? v1 : (pj == 1) ? bl : gl;

    float xr[CIN];
    #pragma unroll
    for (int c = 0; c < CIN; ++c)
        xr[c] = x[c * N + n0 + lane];      // coalesced 256B per load

    #pragma unroll
    for (int i = 0; i < 4; ++i) {
        const int    co = coq * 4 + i;
        const float* wr = w + co * CIN;    // wave-uniform -> s_load
        float acc = 0.f;
        #pragma unroll
        for (int c = 0; c < CIN; ++c)
            acc = fmaf(wr[c], xr[c], acc);
        o[co * N + n0 + lane] = acc + b[co];
    }
}

// ---------------------------------------------------------------------------
// K2: per-channel Taylor moments, no LDS, no barriers. 32 blocks x 256.
// Wave w owns powers k = 4w+1..4w+4 (b^{4w} jump + 4 muls); every wave streams
// the whole channel row (18KB x2, L2-hot). In-wave butterfly; lane0 writes
// coeff_t[c][0][k] = (sum b^k)/k!, coeff_t[c][1][k] = (sum b^k g)/k!.
// ---------------------------------------------------------------------------
__global__ __launch_bounds__(256) void k_mom(
    const float* __restrict__ bl, const float* __restrict__ gl,
    float* __restrict__ coeff)
{
    const int c    = blockIdx.x;
    const int lane = threadIdx.x & 63;
    const int w    = threadIdx.x >> 6;     // 0..3 (wave-uniform)

    const float* bp = bl + c * N;
    const float* gp = gl + c * N;

    float d[4]  = {0.f, 0.f, 0.f, 0.f};
    float nm[4] = {0.f, 0.f, 0.f, 0.f};
    float n0s   = 0.f;

    for (int j4 = lane; j4 < N / 4; j4 += 64) {
        float4 b4 = *(const float4*)&bp[j4 * 4];
        float4 g4 = *(const float4*)&gp[j4 * 4];
        #pragma unroll
        for (int e = 0; e < 4; ++e) {
            float bb = (e==0) ? b4.x : (e==1) ? b4.y : (e==2) ? b4.z : b4.w;
            float gg = (e==0) ? g4.x : (e==1) ? g4.y : (e==2) ? g4.z : g4.w;
            float b2 = bb * bb, b4v = b2 * b2;
            float pw0 = (w == 0) ? 1.0f
                      : (w == 1) ? b4v
                      : (w == 2) ? b4v * b4v
                                 : (b4v * b4v) * b4v;   // b^{4w}, uniform sel
            float p1 = pw0 * bb;                        // b^{4w+1}
            float p2 = p1 * bb;
            float p3 = p2 * bb;
            float p4 = p3 * bb;
            d[0] += p1; nm[0] = fmaf(p1, gg, nm[0]);
            d[1] += p2; nm[1] = fmaf(p2, gg, nm[1]);
            d[2] += p3; nm[2] = fmaf(p3, gg, nm[2]);
            d[3] += p4; nm[3] = fmaf(p4, gg, nm[3]);
            n0s += gg;
        }
    }

    #pragma unroll
    for (int off = 32; off > 0; off >>= 1) {
        #pragma unroll
        for (int i = 0; i < 4; ++i) {
            d[i]  += __shfl_xor(d[i],  off);
            nm[i] += __shfl_xor(nm[i], off);
        }
        n0s += __shfl_xor(n0s, off);
    }

    if (lane == 0) {
        float* row = coeff + c * CSTRIDE;
        #pragma unroll
        for (int i = 0; i < 4; ++i) {
            int k = 4 * w + 1 + i;                     // 1..16 covered
            row[k]      = d[i]  * INVF_C[k];
            row[20 + k] = nm[i] * INVF_C[k];
        }
        if (w == 0) {
            row[0]  = (float)N;                        // k=0: sum b^0
            row[20] = n0s;                             // k=0: sum g
        }
    }
}

// ---------------------------------------------------------------------------
// K3: y = num(a)/den(a) Horner; z = kw@y + kb; out = x + z. TILE=16, 144 blks.
// coeffs as [c][2][20] float4 loads; ys transposed [pos][36] (aligned float4).
// ---------------------------------------------------------------------------
__global__ __launch_bounds__(256) void k_eval(
    const float* __restrict__ x,
    const float* __restrict__ kw, const float* __restrict__ kb,
    const float* __restrict__ v1, const float* __restrict__ coeff,
    float* __restrict__ out)
{
    __shared__ float kwt[CHALF][68];            // [c][co], 272B rows (16B mult)
    __shared__ __align__(16) float cfl[NCOEF_T];// 5.1 KB
    __shared__ float ys[16][36];                // [pos][c], 144B rows (16B mult)
    __shared__ float kbs[CIN];

    const int tid = threadIdx.x;
    const int n0  = blockIdx.x * 16;

    for (int idx = tid; idx < CIN * CHALF; idx += 256) {
        int co = idx >> 5, c = idx & 31;
        kwt[c][co] = kw[idx];                   // kw row-major [co][c]
    }
    if (tid < CIN) kbs[tid] = kb[tid];
    for (int i4 = tid; i4 < NCOEF_T / 4; i4 += 256)
        *(float4*)&cfl[i4 * 4] = *(const float4*)&coeff[i4 * 4];
    __syncthreads();

    // ---- Horner: thread = (c = tid>>3, pp = tid&7), 2 positions ------------
    {
        const int c  = tid >> 3;
        const int pp = tid & 7;
        float dc[20], nc[20];
        #pragma unroll
        for (int q = 0; q < 5; ++q) {
            *(float4*)&dc[q * 4] = *(const float4*)&cfl[c * CSTRIDE + q * 4];
            *(float4*)&nc[q * 4] = *(const float4*)&cfl[c * CSTRIDE + 20 + q * 4];
        }
        float2 a2 = *(const float2*)&v1[c * N + n0 + pp * 2];
        #pragma unroll
        for (int e = 0; e < 2; ++e) {
            float a   = e ? a2.y : a2.x;
            float den = dc[KT - 1], num = nc[KT - 1];
            #pragma unroll
            for (int k = KT - 2; k >= 0; --k) {
                den = fmaf(den, a, dc[k]);
                num = fmaf(num, a, nc[k]);
            }
            ys[pp * 2 + e][c] = num / den;
        }
    }
    __syncthreads();

    // ---- out-projection: thread = (pos = tid&15, coq = tid>>4) -------------
    {
        const int pos = tid & 15;
        const int coq = tid >> 4;               // 0..15 -> co = coq*4 + i
        float yv[CHALF];
        #pragma unroll
        for (int q = 0; q < 8; ++q)
            *(float4*)&yv[q * 4] = *(const float4*)&ys[pos][q * 4];

        float acc[4] = {0.f, 0.f, 0.f, 0.f};
        #pragma unroll
        for (int c = 0; c < CHALF; ++c) {
            float4 wv = *(const float4*)&kwt[c][coq * 4];
            acc[0] = fmaf(wv.x, yv[c], acc[0]);
            acc[1] = fmaf(wv.y, yv[c], acc[1]);
            acc[2] = fmaf(wv.z, yv[c], acc[2]);
            acc[3] = fmaf(wv.w, yv[c], acc[3]);
        }
        #pragma unroll
        for (int i = 0; i < 4; ++i) {
            int off = (coq * 4 + i) * N + n0 + pos;
            out[off] = x[off] + acc[i] + kbs[coq * 4 + i];
        }
    }
}

// ---------------------------------------------------------------------------
extern "C" void kernel_launch(void* const* d_in, const int* in_sizes, int n_in,
                              void* d_out, int out_size, void* d_ws, size_t ws_size,
                              hipStream_t stream)
{
    const float* x  = (const float*)d_in[0];
    const float* tw = (const float*)d_in[1];
    const float* tb = (const float*)d_in[2];
    const float* pw = (const float*)d_in[3];
    const float* pb = (const float*)d_in[4];
    const float* gw = (const float*)d_in[5];
    const float* gb = (const float*)d_in[6];
    const float* kw = (const float*)d_in[7];
    const float* kb = (const float*)d_in[8];
    float* out = (float*)d_out;

    // workspace (floats): v1 @0, bl @73728, gl @147456, coeff_t @221184 (1280)
    float* ws    = (float*)d_ws;
    float* v1    = ws;
    float* bl    = ws + 73728;
    float* gl    = ws + 147456;
    float* coeff = ws + 221184;

    k_proj<<<dim3(N / 64, 24), dim3(64), 0, stream>>>(
        x, tw, tb, pw, pb, gw, gb, v1, bl, gl);

    k_mom<<<dim3(CHALF), dim3(256), 0, stream>>>(bl, gl, coeff);

    k_eval<<<dim3(N / 16), dim3(256), 0, stream>>>(
        x, kw, kb, v1, coeff, out);
}